// Round 2
// baseline (323.689 us; speedup 1.0000x reference)
//
#include <hip/hip_runtime.h>
#include <stdint.h>

typedef __attribute__((ext_vector_type(4))) float f32x4;
typedef __attribute__((ext_vector_type(8))) __bf16 bf16x8;
typedef __attribute__((ext_vector_type(8))) unsigned short u16x8;

typedef __attribute__((address_space(1))) const unsigned int guint;
typedef __attribute__((address_space(3))) unsigned int luint;

__device__ __forceinline__ void gload_lds16(const void* g, void* l) {
  __builtin_amdgcn_global_load_lds((guint*)g, (luint*)l, 16, 0, 0);
}

__device__ __forceinline__ unsigned short f2bf(float f) {
  unsigned int u = __builtin_bit_cast(unsigned int, f);
  u += 0x7fffu + ((u >> 16) & 1u);   // RNE
  return (unsigned short)(u >> 16);
}

// ---------------- fp32 -> bf16 convert, 8 elems/thread ----------------
__global__ __launch_bounds__(256) void cvt_f32_bf16(const float* __restrict__ in,
                                                    unsigned short* __restrict__ out,
                                                    int n) {
  int i = ((int)blockIdx.x * 256 + (int)threadIdx.x) * 8;
  if (i >= n) return;
  float4 a = *(const float4*)(in + i);
  float4 b = *(const float4*)(in + i + 4);
  u16x8 r;
  r[0] = f2bf(a.x); r[1] = f2bf(a.y); r[2] = f2bf(a.z); r[3] = f2bf(a.w);
  r[4] = f2bf(b.x); r[5] = f2bf(b.y); r[6] = f2bf(b.z); r[7] = f2bf(b.w);
  *(u16x8*)(out + i) = r;
}

// ---------------- GEMM: C[M,N] = A[M,K] @ Bw[N,K]^T, epilogue (acc+bias)*alpha
// OUTF32=0: bf16 out; OUTF32=1: f32 out. 128x128 tile, BK=32, 4 waves.
template <int OUTF32>
__global__ __launch_bounds__(256) void gemm_bt(const unsigned short* __restrict__ A,
                                               const unsigned short* __restrict__ Bw,
                                               const float* __restrict__ bias,
                                               void* __restrict__ Cout,
                                               int M, int N, int K, float alpha) {
  __shared__ __align__(16) unsigned short As[128 * 32];
  __shared__ __align__(16) unsigned short Bs[128 * 32];
  const int tid = threadIdx.x;
  const int lane = tid & 63;
  const int wave = tid >> 6;
  const int wr = wave >> 1, wc = wave & 1;
  const int ln = lane & 15, lg = lane >> 4;

  // XCD-aware bijective swizzle (nwg % 8 == 0 for our launches)
  const int nwg = (int)gridDim.x;
  int bid = (int)blockIdx.x;
  int swz = (bid & 7) * (nwg >> 3) + (bid >> 3);
  const int nbn = N >> 7;
  const int bm = swz / nbn, bn = swz % nbn;
  const int row0 = bm << 7, col0 = bn << 7;

  f32x4 acc[4][4] = {};

  for (int kt = 0; kt < K; kt += 32) {
    __syncthreads();
#pragma unroll
    for (int c = 0; c < 2; ++c) {
      int idx = c * 256 + tid;
      int r = idx >> 2, cg = idx & 3;
      gload_lds16(A + (row0 + r) * K + kt + cg * 8, &As[idx * 8]);
    }
#pragma unroll
    for (int c = 0; c < 2; ++c) {
      int idx = c * 256 + tid;
      int r = idx >> 2, cg = idx & 3;
      gload_lds16(Bw + (col0 + r) * K + kt + cg * 8, &Bs[idx * 8]);
    }
    __syncthreads();
    bf16x8 a[4], b[4];
#pragma unroll
    for (int mi = 0; mi < 4; ++mi)
      a[mi] = *(const bf16x8*)&As[(wr * 64 + mi * 16 + ln) * 32 + lg * 8];
#pragma unroll
    for (int ni = 0; ni < 4; ++ni)
      b[ni] = *(const bf16x8*)&Bs[(wc * 64 + ni * 16 + ln) * 32 + lg * 8];
#pragma unroll
    for (int mi = 0; mi < 4; ++mi)
#pragma unroll
      for (int ni = 0; ni < 4; ++ni)
        acc[mi][ni] = __builtin_amdgcn_mfma_f32_16x16x32_bf16(a[mi], b[ni], acc[mi][ni], 0, 0, 0);
  }

#pragma unroll
  for (int mi = 0; mi < 4; ++mi)
#pragma unroll
    for (int ni = 0; ni < 4; ++ni) {
      int n = col0 + wc * 64 + ni * 16 + ln;
      float bv = bias[n];
#pragma unroll
      for (int r = 0; r < 4; ++r) {
        int m = row0 + wr * 64 + mi * 16 + lg * 4 + r;
        float v = (acc[mi][ni][r] + bv) * alpha;
        if (OUTF32)
          ((float*)Cout)[(size_t)m * N + n] = v;
        else
          ((unsigned short*)Cout)[(size_t)m * N + n] = f2bf(v);
      }
    }
}

// ---------------- V transpose per head: [32][2048][64] -> [32][64][2048] ----
// FIXED (R1): each thread now covers 16 elems (2 passes) so the full 64x64
// tile (4096 elems) is read AND written; previous version covered half.
__global__ __launch_bounds__(256) void transpose_v(const unsigned short* __restrict__ V,
                                                   unsigned short* __restrict__ Vt) {
  __shared__ unsigned short t[64][65];
  const int g = (int)blockIdx.x >> 5;
  const int kt = (int)blockIdx.x & 31;
  const int tid = threadIdx.x;
  const int base = g << 17;  // g * 2048 * 64
#pragma unroll
  for (int h = 0; h < 2; ++h) {
    int key = (tid >> 3) + h * 32, d0 = (tid & 7) * 8;
    u16x8 v = *(const u16x8*)(V + base + (kt * 64 + key) * 64 + d0);
#pragma unroll
    for (int j = 0; j < 8; ++j) t[d0 + j][key] = v[j];
  }
  __syncthreads();
#pragma unroll
  for (int h = 0; h < 2; ++h) {
    int d = (tid >> 3) + h * 32, k0 = (tid & 7) * 8;
    u16x8 r;
#pragma unroll
    for (int j = 0; j < 8; ++j) r[j] = t[d][k0 + j];
    *(u16x8*)(Vt + base + d * 2048 + kt * 64 + k0) = r;
  }
}

// ---------------- Flash attention over 32 heads of [2048,64] ----------------
// Q pre-scaled by 1/8. K: [g][2048][64]. Vt: [g][64][2048]. O: [g][2048][64] bf16.
// Block: 128 Q rows (4 waves x 32 rows). KV tile = 64.
__global__ __launch_bounds__(256) void attn_kernel(const unsigned short* __restrict__ Q,
                                                   const unsigned short* __restrict__ Km,
                                                   const unsigned short* __restrict__ Vt,
                                                   unsigned short* __restrict__ O) {
  __shared__ __align__(16) unsigned short Ks[64 * 64];
  __shared__ __align__(16) unsigned short Vs[64 * 64];
  __shared__ __align__(16) unsigned short Ps[4][32 * 64];
  const int tid = threadIdx.x;
  const int lane = tid & 63, wave = tid >> 6;
  const int ln = lane & 15, lg = lane >> 4;

  // XCD swizzle: all 16 q-tiles of a head (plus 4 heads) per XCD for K/V L2 reuse
  const int bid = (int)blockIdx.x;
  const int g = (bid & 7) + (bid >> 7) * 8;
  const int qt = (bid >> 3) & 15;
  const int base = g << 17;
  const int qrow0 = qt * 128 + wave * 32;

  bf16x8 aq[2][2];
#pragma unroll
  for (int mb = 0; mb < 2; ++mb)
#pragma unroll
    for (int kb = 0; kb < 2; ++kb)
      aq[mb][kb] = *(const bf16x8*)(Q + base + (qrow0 + mb * 16 + ln) * 64 + kb * 32 + lg * 8);

  float m_i[2][4], l_i[2][4];
#pragma unroll
  for (int mb = 0; mb < 2; ++mb)
#pragma unroll
    for (int r = 0; r < 4; ++r) { m_i[mb][r] = -1e30f; l_i[mb][r] = 0.f; }
  f32x4 acc_o[2][4] = {};

  unsigned short* Pw = &Ps[wave][0];

  for (int kv = 0; kv < 32; ++kv) {
    __syncthreads();
    // stage K tile [64 keys][64 d], XOR-swizzled via pre-swizzled global source
#pragma unroll
    for (int c = 0; c < 2; ++c) {
      int idx = c * 256 + tid;
      int r = idx >> 3, cg = idx & 7;
      gload_lds16(Km + base + (kv * 64 + r) * 64 + ((cg ^ (r & 7)) * 8), &Ks[idx * 8]);
    }
    // stage Vt tile [64 d][64 keys], same swizzle
#pragma unroll
    for (int c = 0; c < 2; ++c) {
      int idx = c * 256 + tid;
      int r = idx >> 3, cg = idx & 7;
      gload_lds16(Vt + base + r * 2048 + kv * 64 + ((cg ^ (r & 7)) * 8), &Vs[idx * 8]);
    }
    __syncthreads();

    // S = Q @ K^T  (rows=queries, cols=keys)
    f32x4 acc_s[2][4] = {};
#pragma unroll
    for (int kb = 0; kb < 2; ++kb) {
#pragma unroll
      for (int nb = 0; nb < 4; ++nb) {
        int krow = nb * 16 + ln;
        bf16x8 bk = *(const bf16x8*)&Ks[krow * 64 + (((kb * 4 + lg) ^ (krow & 7)) * 8)];
#pragma unroll
        for (int mb = 0; mb < 2; ++mb)
          acc_s[mb][nb] = __builtin_amdgcn_mfma_f32_16x16x32_bf16(aq[mb][kb], bk, acc_s[mb][nb], 0, 0, 0);
      }
    }

    // online softmax (row r_abs = mb*16 + lg*4 + r; keys spread over ln + nb)
    float p[2][4][4];
#pragma unroll
    for (int mb = 0; mb < 2; ++mb) {
#pragma unroll
      for (int r = 0; r < 4; ++r) {
        float mx = fmaxf(fmaxf(acc_s[mb][0][r], acc_s[mb][1][r]),
                         fmaxf(acc_s[mb][2][r], acc_s[mb][3][r]));
        mx = fmaxf(mx, __shfl_xor(mx, 1));
        mx = fmaxf(mx, __shfl_xor(mx, 2));
        mx = fmaxf(mx, __shfl_xor(mx, 4));
        mx = fmaxf(mx, __shfl_xor(mx, 8));
        float mnew = fmaxf(m_i[mb][r], mx);
        float scale = exp2f((m_i[mb][r] - mnew) * 1.44269504f);
        m_i[mb][r] = mnew;
        float ps = 0.f;
#pragma unroll
        for (int nb = 0; nb < 4; ++nb) {
          float pv = exp2f((acc_s[mb][nb][r] - mnew) * 1.44269504f);
          p[mb][nb][r] = pv;
          ps += pv;
        }
        ps += __shfl_xor(ps, 1);
        ps += __shfl_xor(ps, 2);
        ps += __shfl_xor(ps, 4);
        ps += __shfl_xor(ps, 8);
        l_i[mb][r] = l_i[mb][r] * scale + ps;
#pragma unroll
        for (int nd = 0; nd < 4; ++nd) acc_o[mb][nd][r] *= scale;
      }
    }

    // P -> per-wave LDS (bf16, XOR-swizzled rows)
#pragma unroll
    for (int mb = 0; mb < 2; ++mb)
#pragma unroll
      for (int r = 0; r < 4; ++r) {
        int row = mb * 16 + lg * 4 + r;
        int x8 = (row & 7) * 8;
#pragma unroll
        for (int nb = 0; nb < 4; ++nb)
          Pw[row * 64 + ((nb * 16 + ln) ^ x8)] = f2bf(p[mb][nb][r]);
      }

    // O += P @ V  (A=P [qrow][key], B=Vt [d][key])
#pragma unroll
    for (int kb = 0; kb < 2; ++kb) {
      bf16x8 ap[2];
#pragma unroll
      for (int mb = 0; mb < 2; ++mb) {
        int row = mb * 16 + ln;
        ap[mb] = *(const bf16x8*)&Pw[row * 64 + ((kb * 32 + lg * 8) ^ ((row & 7) * 8))];
      }
#pragma unroll
      for (int nd = 0; nd < 4; ++nd) {
        int drow = nd * 16 + ln;
        bf16x8 bv = *(const bf16x8*)&Vs[drow * 64 + (((kb * 4 + lg) ^ (drow & 7)) * 8)];
#pragma unroll
        for (int mb = 0; mb < 2; ++mb)
          acc_o[mb][nd] = __builtin_amdgcn_mfma_f32_16x16x32_bf16(ap[mb], bv, acc_o[mb][nd], 0, 0, 0);
      }
    }
  }

  // epilogue: O = acc / l
#pragma unroll
  for (int mb = 0; mb < 2; ++mb)
#pragma unroll
    for (int r = 0; r < 4; ++r) {
      float inv = 1.f / l_i[mb][r];
      int row = qrow0 + mb * 16 + lg * 4 + r;
#pragma unroll
      for (int nd = 0; nd < 4; ++nd)
        O[base + row * 64 + nd * 16 + ln] = f2bf(acc_o[mb][nd][r] * inv);
    }
}

// ---------------- launch ----------------
extern "C" void kernel_launch(void* const* d_in, const int* in_sizes, int n_in,
                              void* d_out, int out_size, void* d_ws, size_t ws_size,
                              hipStream_t stream) {
  const float* query = (const float*)d_in[0];
  const float* key   = (const float*)d_in[1];
  const float* value = (const float*)d_in[2];
  const float* Wq = (const float*)d_in[3];
  const float* bq = (const float*)d_in[4];
  const float* Wk = (const float*)d_in[5];
  const float* bk = (const float*)d_in[6];
  const float* Wv = (const float*)d_in[7];
  const float* bv = (const float*)d_in[8];
  const float* Wo = (const float*)d_in[9];
  const float* bo = (const float*)d_in[10];

  const int ACT = 4096 * 1024;   // activation elems
  const int WEL = 1024 * 1024;   // weight elems

  // Workspace layout (34 MB, aliased):
  //   X    @ 0        (8 MB)  bf16 input activations; DEAD after V-proj GEMM
  //   Vtb  @ 0        (8 MB)  aliases X (transpose runs after V GEMM)
  //   W    @ 8 MB     (2 MB)  current weight bf16
  //   Qb   @ 10 MB    (8 MB)
  //   Kb   @ 18 MB    (8 MB)
  //   Vb   @ 26 MB    (8 MB)  DEAD after transpose
  //   Ob   @ 26 MB            aliases Vb (attn writes after transpose)
  char* ws = (char*)d_ws;
  unsigned short* X   = (unsigned short*)(ws);
  unsigned short* Vtb = (unsigned short*)(ws);
  unsigned short* W   = (unsigned short*)(ws + 8388608);
  unsigned short* Qb  = (unsigned short*)(ws + 10485760);
  unsigned short* Kb  = (unsigned short*)(ws + 18874368);
  unsigned short* Vb  = (unsigned short*)(ws + 27262976);
  unsigned short* Ob  = (unsigned short*)(ws + 27262976);

  dim3 blk(256);
  const int M = 4096, N = 1024, Kd = 1024;

  // Q projection (scale 1/sqrt(64) fused)
  cvt_f32_bf16<<<dim3(ACT / 2048), blk, 0, stream>>>(query, X, ACT);
  cvt_f32_bf16<<<dim3(WEL / 2048), blk, 0, stream>>>(Wq, W, WEL);
  gemm_bt<0><<<dim3(256), blk, 0, stream>>>(X, W, bq, (void*)Qb, M, N, Kd, 0.125f);

  // K projection
  cvt_f32_bf16<<<dim3(ACT / 2048), blk, 0, stream>>>(key, X, ACT);
  cvt_f32_bf16<<<dim3(WEL / 2048), blk, 0, stream>>>(Wk, W, WEL);
  gemm_bt<0><<<dim3(256), blk, 0, stream>>>(X, W, bk, (void*)Kb, M, N, Kd, 1.0f);

  // V projection
  cvt_f32_bf16<<<dim3(ACT / 2048), blk, 0, stream>>>(value, X, ACT);
  cvt_f32_bf16<<<dim3(WEL / 2048), blk, 0, stream>>>(Wv, W, WEL);
  gemm_bt<0><<<dim3(256), blk, 0, stream>>>(X, W, bv, (void*)Vb, M, N, Kd, 1.0f);

  // V transpose per head (Vb -> Vtb, which aliases the now-dead X)
  transpose_v<<<dim3(1024), blk, 0, stream>>>(Vb, Vtb);

  // Wo convert (W buffer free now)
  cvt_f32_bf16<<<dim3(WEL / 2048), blk, 0, stream>>>(Wo, W, WEL);

  // attention (writes Ob, which aliases the now-dead Vb)
  attn_kernel<<<dim3(512), blk, 0, stream>>>(Qb, Kb, Vtb, Ob);

  // output projection, fp32 out
  gemm_bt<1><<<dim3(256), blk, 0, stream>>>(Ob, W, bo, d_out, M, N, Kd, 1.0f);
}

// Round 3
// 291.909 us; speedup vs baseline: 1.1089x; 1.1089x over previous
//
#include <hip/hip_runtime.h>
#include <stdint.h>

typedef __attribute__((ext_vector_type(4))) float f32x4;
typedef __attribute__((ext_vector_type(8))) __bf16 bf16x8;
typedef __attribute__((ext_vector_type(8))) unsigned short u16x8;

typedef __attribute__((address_space(1))) const unsigned int guint;
typedef __attribute__((address_space(3))) unsigned int luint;

__device__ __forceinline__ void gload_lds16(const void* g, void* l) {
  __builtin_amdgcn_global_load_lds((guint*)g, (luint*)l, 16, 0, 0);
}

__device__ __forceinline__ unsigned short f2bf(float f) {
  unsigned int u = __builtin_bit_cast(unsigned int, f);
  u += 0x7fffu + ((u >> 16) & 1u);   // RNE
  return (unsigned short)(u >> 16);
}

// ---------------- fp32 -> bf16 convert, 8 elems/thread ----------------
__global__ __launch_bounds__(256) void cvt_f32_bf16(const float* __restrict__ in,
                                                    unsigned short* __restrict__ out,
                                                    int n) {
  int i = ((int)blockIdx.x * 256 + (int)threadIdx.x) * 8;
  if (i >= n) return;
  float4 a = *(const float4*)(in + i);
  float4 b = *(const float4*)(in + i + 4);
  u16x8 r;
  r[0] = f2bf(a.x); r[1] = f2bf(a.y); r[2] = f2bf(a.z); r[3] = f2bf(a.w);
  r[4] = f2bf(b.x); r[5] = f2bf(b.y); r[6] = f2bf(b.z); r[7] = f2bf(b.w);
  *(u16x8*)(out + i) = r;
}

// ---------------- GEMM: C[M,N] = A[M,K] @ Bw[N,K]^T, epilogue (acc+bias)*alpha
template <int OUTF32>
__global__ __launch_bounds__(256) void gemm_bt(const unsigned short* __restrict__ A,
                                               const unsigned short* __restrict__ Bw,
                                               const float* __restrict__ bias,
                                               void* __restrict__ Cout,
                                               int M, int N, int K, float alpha) {
  __shared__ __align__(16) unsigned short As[128 * 32];
  __shared__ __align__(16) unsigned short Bs[128 * 32];
  const int tid = threadIdx.x;
  const int lane = tid & 63;
  const int wave = tid >> 6;
  const int wr = wave >> 1, wc = wave & 1;
  const int ln = lane & 15, lg = lane >> 4;

  const int nwg = (int)gridDim.x;
  int bid = (int)blockIdx.x;
  int swz = (bid & 7) * (nwg >> 3) + (bid >> 3);
  const int nbn = N >> 7;
  const int bm = swz / nbn, bn = swz % nbn;
  const int row0 = bm << 7, col0 = bn << 7;

  f32x4 acc[4][4] = {};

  for (int kt = 0; kt < K; kt += 32) {
    __syncthreads();
#pragma unroll
    for (int c = 0; c < 2; ++c) {
      int idx = c * 256 + tid;
      int r = idx >> 2, cg = idx & 3;
      gload_lds16(A + (row0 + r) * K + kt + cg * 8, &As[idx * 8]);
    }
#pragma unroll
    for (int c = 0; c < 2; ++c) {
      int idx = c * 256 + tid;
      int r = idx >> 2, cg = idx & 3;
      gload_lds16(Bw + (col0 + r) * K + kt + cg * 8, &Bs[idx * 8]);
    }
    __syncthreads();
    bf16x8 a[4], b[4];
#pragma unroll
    for (int mi = 0; mi < 4; ++mi)
      a[mi] = *(const bf16x8*)&As[(wr * 64 + mi * 16 + ln) * 32 + lg * 8];
#pragma unroll
    for (int ni = 0; ni < 4; ++ni)
      b[ni] = *(const bf16x8*)&Bs[(wc * 64 + ni * 16 + ln) * 32 + lg * 8];
#pragma unroll
    for (int mi = 0; mi < 4; ++mi)
#pragma unroll
      for (int ni = 0; ni < 4; ++ni)
        acc[mi][ni] = __builtin_amdgcn_mfma_f32_16x16x32_bf16(a[mi], b[ni], acc[mi][ni], 0, 0, 0);
  }

#pragma unroll
  for (int mi = 0; mi < 4; ++mi)
#pragma unroll
    for (int ni = 0; ni < 4; ++ni) {
      int n = col0 + wc * 64 + ni * 16 + ln;
      float bv = bias[n];
#pragma unroll
      for (int r = 0; r < 4; ++r) {
        int m = row0 + wr * 64 + mi * 16 + lg * 4 + r;
        float v = (acc[mi][ni][r] + bv) * alpha;
        if (OUTF32)
          ((float*)Cout)[(size_t)m * N + n] = v;
        else
          ((unsigned short*)Cout)[(size_t)m * N + n] = f2bf(v);
      }
    }
}

// ---------------- V transpose per head: [32][2048][64] -> [32][64][2048] ----
__global__ __launch_bounds__(256) void transpose_v(const unsigned short* __restrict__ V,
                                                   unsigned short* __restrict__ Vt) {
  __shared__ unsigned short t[64][65];
  const int g = (int)blockIdx.x >> 5;
  const int kt = (int)blockIdx.x & 31;
  const int tid = threadIdx.x;
  const int base = g << 17;  // g * 2048 * 64
#pragma unroll
  for (int h = 0; h < 2; ++h) {
    int key = (tid >> 3) + h * 32, d0 = (tid & 7) * 8;
    u16x8 v = *(const u16x8*)(V + base + (kt * 64 + key) * 64 + d0);
#pragma unroll
    for (int j = 0; j < 8; ++j) t[d0 + j][key] = v[j];
  }
  __syncthreads();
#pragma unroll
  for (int h = 0; h < 2; ++h) {
    int d = (tid >> 3) + h * 32, k0 = (tid & 7) * 8;
    u16x8 r;
#pragma unroll
    for (int j = 0; j < 8; ++j) r[j] = t[d][k0 + j];
    *(u16x8*)(Vt + base + d * 2048 + kt * 64 + k0) = r;
  }
}

// ---------------- Flash attention over 32 heads of [2048,64] ----------------
// Q pre-scaled by (1/8)*log2(e): S is in log2 units, exp2 used directly.
// K: [g][2048][64]. Vt: [g][64][2048]. O: [g][2048][64] bf16.
// R3: no LDS K/V staging (L2-resident), no __syncthreads — waves free-run.
// 1024 blocks x 128 threads (2 waves x 32 Q-rows); per-wave private P in LDS.
__global__ __launch_bounds__(128) void attn_kernel(const unsigned short* __restrict__ Q,
                                                   const unsigned short* __restrict__ Km,
                                                   const unsigned short* __restrict__ Vt,
                                                   unsigned short* __restrict__ O) {
  __shared__ __align__(16) unsigned short Ps[2][32 * 64];
  const int tid = threadIdx.x;
  const int lane = tid & 63, wave = tid >> 6;
  const int ln = lane & 15, lg = lane >> 4;

  // XCD swizzle: 4 heads x 32 q-tiles per XCD (1024 blocks)
  const int bid = (int)blockIdx.x;
  const int g = (bid & 7) + ((bid >> 8) << 3);
  const int qt = (bid >> 3) & 31;
  const int base = g << 17;
  const int qrow0 = qt * 64 + wave * 32;

  bf16x8 aq[2][2];
#pragma unroll
  for (int mb = 0; mb < 2; ++mb)
#pragma unroll
    for (int kb = 0; kb < 2; ++kb)
      aq[mb][kb] = *(const bf16x8*)(Q + base + (qrow0 + mb * 16 + ln) * 64 + kb * 32 + lg * 8);

  float m_i[2][4], l_p[2][4];
#pragma unroll
  for (int mb = 0; mb < 2; ++mb)
#pragma unroll
    for (int r = 0; r < 4; ++r) { m_i[mb][r] = -1e30f; l_p[mb][r] = 0.f; }
  f32x4 acc_o[2][4] = {};

  unsigned short* Pw = &Ps[wave][0];

  for (int kv = 0; kv < 32; ++kv) {
    const unsigned short* Kt = Km + base + (kv << 12);  // kv*64*64

    // ---- S = Q @ K^T, B-fragments straight from L2 ----
    f32x4 acc_s[2][4] = {};
    __builtin_amdgcn_s_setprio(1);
#pragma unroll
    for (int kb = 0; kb < 2; ++kb) {
#pragma unroll
      for (int nb = 0; nb < 4; ++nb) {
        bf16x8 bk = *(const bf16x8*)(Kt + (nb * 16 + ln) * 64 + kb * 32 + lg * 8);
#pragma unroll
        for (int mb = 0; mb < 2; ++mb)
          acc_s[mb][nb] = __builtin_amdgcn_mfma_f32_16x16x32_bf16(aq[mb][kb], bk, acc_s[mb][nb], 0, 0, 0);
      }
    }
    __builtin_amdgcn_s_setprio(0);

    // ---- online softmax (log2 units) ----
    float mx[2][4];
    int grow = 0;
#pragma unroll
    for (int mb = 0; mb < 2; ++mb)
#pragma unroll
      for (int r = 0; r < 4; ++r) {
        float m4 = fmaxf(fmaxf(acc_s[mb][0][r], acc_s[mb][1][r]),
                         fmaxf(acc_s[mb][2][r], acc_s[mb][3][r]));
        m4 = fmaxf(m4, __shfl_xor(m4, 1));
        m4 = fmaxf(m4, __shfl_xor(m4, 2));
        m4 = fmaxf(m4, __shfl_xor(m4, 4));
        m4 = fmaxf(m4, __shfl_xor(m4, 8));
        mx[mb][r] = m4;
        grow |= (m4 > m_i[mb][r] + 8.0f);
      }
    if (__any(grow)) {   // rescale path (rare after first tiles)
#pragma unroll
      for (int mb = 0; mb < 2; ++mb)
#pragma unroll
        for (int r = 0; r < 4; ++r) {
          float mnew = fmaxf(m_i[mb][r], mx[mb][r]);
          float scale = exp2f(m_i[mb][r] - mnew);
          m_i[mb][r] = mnew;
          l_p[mb][r] *= scale;
#pragma unroll
          for (int nd = 0; nd < 4; ++nd) acc_o[mb][nd][r] *= scale;
        }
    }
    // p = exp2(S - m), store bf16 to per-wave LDS, per-lane partial l
#pragma unroll
    for (int mb = 0; mb < 2; ++mb)
#pragma unroll
      for (int r = 0; r < 4; ++r) {
        int row = mb * 16 + lg * 4 + r;
        int x8 = (row & 7) * 8;
        float ls = 0.f;
#pragma unroll
        for (int nb = 0; nb < 4; ++nb) {
          float pv = exp2f(acc_s[mb][nb][r] - m_i[mb][r]);
          Pw[row * 64 + ((nb * 16 + ln) ^ x8)] = f2bf(pv);
          ls += pv;
        }
        l_p[mb][r] += ls;
      }

    asm volatile("s_waitcnt lgkmcnt(0)" ::: "memory");
    __builtin_amdgcn_sched_barrier(0);

    // ---- O += P @ V, B-fragments straight from L2 ----
    const unsigned short* Vb2 = Vt + base + kv * 64;
    __builtin_amdgcn_s_setprio(1);
#pragma unroll
    for (int kb = 0; kb < 2; ++kb) {
      bf16x8 ap[2];
#pragma unroll
      for (int mb = 0; mb < 2; ++mb) {
        int row = mb * 16 + ln;
        ap[mb] = *(const bf16x8*)&Pw[row * 64 + ((kb * 32 + lg * 8) ^ ((row & 7) * 8))];
      }
#pragma unroll
      for (int nd = 0; nd < 4; ++nd) {
        bf16x8 bv = *(const bf16x8*)(Vb2 + (nd * 16 + ln) * 2048 + (kb * 4 + lg) * 8);
#pragma unroll
        for (int mb = 0; mb < 2; ++mb)
          acc_o[mb][nd] = __builtin_amdgcn_mfma_f32_16x16x32_bf16(ap[mb], bv, acc_o[mb][nd], 0, 0, 0);
      }
    }
    __builtin_amdgcn_s_setprio(0);
  }

  // final: reduce per-lane partial l over the 16-lane key groups, then divide
#pragma unroll
  for (int mb = 0; mb < 2; ++mb)
#pragma unroll
    for (int r = 0; r < 4; ++r) {
      float ls = l_p[mb][r];
      ls += __shfl_xor(ls, 1);
      ls += __shfl_xor(ls, 2);
      ls += __shfl_xor(ls, 4);
      ls += __shfl_xor(ls, 8);
      float inv = 1.f / ls;
      int row = qrow0 + mb * 16 + lg * 4 + r;
#pragma unroll
      for (int nd = 0; nd < 4; ++nd)
        O[base + row * 64 + nd * 16 + ln] = f2bf(acc_o[mb][nd][r] * inv);
    }
}

// ---------------- launch ----------------
extern "C" void kernel_launch(void* const* d_in, const int* in_sizes, int n_in,
                              void* d_out, int out_size, void* d_ws, size_t ws_size,
                              hipStream_t stream) {
  const float* query = (const float*)d_in[0];
  const float* key   = (const float*)d_in[1];
  const float* value = (const float*)d_in[2];
  const float* Wq = (const float*)d_in[3];
  const float* bq = (const float*)d_in[4];
  const float* Wk = (const float*)d_in[5];
  const float* bk = (const float*)d_in[6];
  const float* Wv = (const float*)d_in[7];
  const float* bv = (const float*)d_in[8];
  const float* Wo = (const float*)d_in[9];
  const float* bo = (const float*)d_in[10];

  const int ACT = 4096 * 1024;   // activation elems
  const int WEL = 1024 * 1024;   // weight elems

  // Workspace layout (34 MB, aliased):
  //   X/Vtb @ 0 (8MB), W @ 8MB (2MB), Qb @ 10MB, Kb @ 18MB, Vb/Ob @ 26MB
  char* ws = (char*)d_ws;
  unsigned short* X   = (unsigned short*)(ws);
  unsigned short* Vtb = (unsigned short*)(ws);
  unsigned short* W   = (unsigned short*)(ws + 8388608);
  unsigned short* Qb  = (unsigned short*)(ws + 10485760);
  unsigned short* Kb  = (unsigned short*)(ws + 18874368);
  unsigned short* Vb  = (unsigned short*)(ws + 27262976);
  unsigned short* Ob  = (unsigned short*)(ws + 27262976);

  dim3 blk(256);
  const int M = 4096, N = 1024, Kd = 1024;

  // Q projection: fold scaling 1/sqrt(64) AND log2(e) so attn S is in log2 units
  cvt_f32_bf16<<<dim3(ACT / 2048), blk, 0, stream>>>(query, X, ACT);
  cvt_f32_bf16<<<dim3(WEL / 2048), blk, 0, stream>>>(Wq, W, WEL);
  gemm_bt<0><<<dim3(256), blk, 0, stream>>>(X, W, bq, (void*)Qb, M, N, Kd, 0.125f * 1.44269504f);

  // K projection
  cvt_f32_bf16<<<dim3(ACT / 2048), blk, 0, stream>>>(key, X, ACT);
  cvt_f32_bf16<<<dim3(WEL / 2048), blk, 0, stream>>>(Wk, W, WEL);
  gemm_bt<0><<<dim3(256), blk, 0, stream>>>(X, W, bk, (void*)Kb, M, N, Kd, 1.0f);

  // V projection
  cvt_f32_bf16<<<dim3(ACT / 2048), blk, 0, stream>>>(value, X, ACT);
  cvt_f32_bf16<<<dim3(WEL / 2048), blk, 0, stream>>>(Wv, W, WEL);
  gemm_bt<0><<<dim3(256), blk, 0, stream>>>(X, W, bv, (void*)Vb, M, N, Kd, 1.0f);

  // V transpose per head (Vb -> Vtb, aliases dead X)
  transpose_v<<<dim3(1024), blk, 0, stream>>>(Vb, Vtb);

  // Wo convert
  cvt_f32_bf16<<<dim3(WEL / 2048), blk, 0, stream>>>(Wo, W, WEL);

  // attention: 1024 blocks x 128 threads
  attn_kernel<<<dim3(1024), dim3(128), 0, stream>>>(Qb, Kb, Vtb, Ob);

  // output projection, fp32 out
  gemm_bt<1><<<dim3(256), blk, 0, stream>>>(Ob, W, bo, d_out, M, N, Kd, 1.0f);
}